// Round 6
// baseline (398.733 us; speedup 1.0000x reference)
//
#include <hip/hip_runtime.h>
#include <cstdint>
#include <cstddef>

// Round 6: gray-code resident-operand 8-phase 256x256 GEMM.
// Quadrant order per tile: Q00,Q01,Q11,Q10 — each phase changes exactly one
// operand set; all MFMA operands (except b0's 4 reads) are read >=1 phase
// before use, so LDS drain hides under MFMA. Peak operand liveness = 64 VGPR
// (R5-proven level) via half-set reads. b0 re-read at phi3 (b0r).
// Stage ledger: region staged only >=1 barrier after its last read's
// consuming MFMA; RAW guard = counted vm(2) at phi3-end.
// y = x_bf16 @ (w*bf16(scale))_bf16^T + bias  (x_dq == x exactly: pow2 scales)

typedef __attribute__((ext_vector_type(8))) __bf16 bf16x8;
typedef __attribute__((ext_vector_type(4))) float f32x4;

__device__ __forceinline__ unsigned short bf16rn(float f) {
  unsigned u = __builtin_bit_cast(unsigned, f);
  u = (u + 0x7FFFu + ((u >> 16) & 1u)) >> 16;
  return (unsigned short)u;
}
__device__ __forceinline__ float bf16tof(unsigned short h) {
  unsigned u = ((unsigned)h) << 16;
  return __builtin_bit_cast(float, u);
}
__device__ __forceinline__ void gload_lds16(const void* g, void* l) {
  __builtin_amdgcn_global_load_lds(
      (const __attribute__((address_space(1))) unsigned int*)g,
      (__attribute__((address_space(3))) unsigned int*)l, 16, 0, 0);
}

// ---------------- Phase A: fused prep (x->bf16, w*scale->bf16) -------------

__global__ __launch_bounds__(256) void k_prep(
    const float* __restrict__ x, const float* __restrict__ w,
    const float* __restrict__ sc, unsigned short* __restrict__ xb,
    unsigned short* __restrict__ wb, int K, int nblk, int blk,
    int n8x, int n8w) {
  int t = blockIdx.x * 256 + threadIdx.x;
  if (t < n8x) {
    const float4* p = (const float4*)x + (size_t)t * 2;
    float4 a = p[0], b = p[1];
    uint4 o;
    o.x = (unsigned)bf16rn(a.x) | ((unsigned)bf16rn(a.y) << 16);
    o.y = (unsigned)bf16rn(a.z) | ((unsigned)bf16rn(a.w) << 16);
    o.z = (unsigned)bf16rn(b.x) | ((unsigned)bf16rn(b.y) << 16);
    o.w = (unsigned)bf16rn(b.z) | ((unsigned)bf16rn(b.w) << 16);
    ((uint4*)xb)[t] = o;
  } else if (t - n8x < n8w) {
    int tw = t - n8x;
    size_t base = (size_t)tw * 8;
    int o_row = (int)(base / (size_t)K);
    int k = (int)(base % (size_t)K);
    float s = bf16tof(bf16rn(sc[(size_t)o_row * nblk + k / blk]));
    const float4* p = (const float4*)w + (size_t)tw * 2;
    float4 a = p[0], b = p[1];
    uint4 o;
    o.x = (unsigned)bf16rn(a.x * s) | ((unsigned)bf16rn(a.y * s) << 16);
    o.y = (unsigned)bf16rn(a.z * s) | ((unsigned)bf16rn(a.w * s) << 16);
    o.z = (unsigned)bf16rn(b.x * s) | ((unsigned)bf16rn(b.y * s) << 16);
    o.w = (unsigned)bf16rn(b.z * s) | ((unsigned)bf16rn(b.w * s) << 16);
    ((uint4*)wb)[tw] = o;
  }
}

// ---------------- Phase B: 256^2 gray-code 8-phase GEMM --------------------

#define BM 256
#define BN 256
#define BK 64

#define BARF()                                  \
  do {                                          \
    __builtin_amdgcn_s_barrier();               \
    asm volatile("" ::: "memory");              \
    __builtin_amdgcn_sched_barrier(0);          \
  } while (0)
#define WAIT_VM(n) asm volatile("s_waitcnt vmcnt(" #n ")" ::: "memory")
#define PRIO(p) __builtin_amdgcn_s_setprio(p)

#define STG_A(buf, q, tile)                                               \
  gload_lds16(Ag + (size_t)(q) * 64 * Ks + (size_t)(tile) * BK,           \
              smem + (buf) * 65536 + (q) * 8192 + tid16)
#define STG_B(buf, q, tile)                                               \
  gload_lds16(Bg + (size_t)(q) * 64 * Ks + (size_t)(tile) * BK,           \
              smem + (buf) * 65536 + 32768 + (q) * 8192 + tid16)

// half A-set: frags hh*2, hh*2+1 (4 x ds_read_b128)
#define READ_AH(arr, buf, qm, hh)                                         \
  _Pragma("unroll") for (int i_ = 0; i_ < 2; ++i_) {                      \
    const int f_ = (hh) * 2 + i_;                                         \
    arr[f_][0] = *(const bf16x8*)(smem + (buf) * 65536 +                  \
        (wr * 128 + (qm) * 64 + f_ * 16 + lr) * 128 + ko0);               \
    arr[f_][1] = *(const bf16x8*)(smem + (buf) * 65536 +                  \
        (wr * 128 + (qm) * 64 + f_ * 16 + lr) * 128 + ko1);               \
  }
#define READ_B(arr, buf, qn)                                              \
  _Pragma("unroll") for (int j_ = 0; j_ < 2; ++j_) {                      \
    arr[j_][0] = *(const bf16x8*)(smem + (buf) * 65536 + 32768 +          \
        (wc * 64 + (qn) * 32 + j_ * 16 + lr) * 128 + ko0);                \
    arr[j_][1] = *(const bf16x8*)(smem + (buf) * 65536 + 32768 +          \
        (wc * 64 + (qn) * 32 + j_ * 16 + lr) * 128 + ko1);                \
  }
#define MFMA_Q(qm, qn, aarr, barr)                                        \
  _Pragma("unroll") for (int kk_ = 0; kk_ < 2; ++kk_)                     \
  _Pragma("unroll") for (int i_ = 0; i_ < 4; ++i_)                        \
  _Pragma("unroll") for (int j_ = 0; j_ < 2; ++j_)                        \
    acc[(qm) * 4 + i_][(qn) * 2 + j_] =                                   \
        __builtin_amdgcn_mfma_f32_16x16x32_bf16(                          \
            aarr[i_][kk_], barr[j_][kk_],                                 \
            acc[(qm) * 4 + i_][(qn) * 2 + j_], 0, 0, 0);

__global__ __launch_bounds__(512, 2) void k_gemm256(
    const unsigned short* __restrict__ A, const unsigned short* __restrict__ B,
    const float* __restrict__ bias, float* __restrict__ C,
    int M, int N, int K) {
  extern __shared__ __align__(16) char smem[];

  const int nbn = N / BN;
  const int nwg = gridDim.x;
  int bid = blockIdx.x;
  int wg = bid;
  if ((nwg & 7) == 0) wg = (bid & 7) * (nwg >> 3) + (bid >> 3);  // T1
  const int m0 = (wg / nbn) * BM;
  const int n0 = (wg % nbn) * BN;

  const int tid = threadIdx.x;
  const int lane = tid & 63;
  const int wid = tid >> 6;
  const int wr = wid >> 2;
  const int wc = wid & 3;
  const int lr = lane & 15;
  const int ko0 = (((lane >> 4) * 16) ^ ((lane & 7) << 4));
  const int ko1 = ((64 | ((lane >> 4) * 16)) ^ ((lane & 7) << 4));
  const int tid16 = tid * 16;

  const int srow = tid >> 3;
  const int sgran = (tid & 7) ^ (srow & 7);  // inverse swizzle on source
  const size_t Ks = (size_t)K;
  const unsigned short* Ag = A + (size_t)(m0 + srow) * Ks + sgran * 8;
  const unsigned short* Bg = B + (size_t)(n0 + srow) * Ks + sgran * 8;

  f32x4 acc[8][4] = {};
  bf16x8 a0[4][2], a1[4][2], b0[2][2], b1[2][2], b0r[2][2];

  const int NT = K / BK;
  const int NITER = NT / 2;

  // prologue: t0 full -> buf0; A02,A13(t1) -> buf1; guard t0; read a0h1(t0)
  STG_A(0, 0, 0); STG_A(0, 2, 0); STG_A(0, 1, 0); STG_A(0, 3, 0);
  STG_B(0, 0, 0); STG_B(0, 1, 0); STG_B(0, 2, 0); STG_B(0, 3, 0);
  STG_A(1, 0, 1); STG_A(1, 2, 1); STG_A(1, 1, 1); STG_A(1, 3, 1);
  WAIT_VM(4);
  BARF();
  READ_AH(a0, 0, 0, 0);

  for (int it = 0; it < NITER; ++it) {
    const int u = 2 * it;
    const bool s1 = (u + 2) < NT;
    const bool s2 = (u + 3) < NT;
    // phi1(u): stage B(u+1)->buf1; reads a0h2,b0,b1(buf0); MFMA Q00
    STG_B(1, 0, u + 1); STG_B(1, 1, u + 1);
    STG_B(1, 2, u + 1); STG_B(1, 3, u + 1);
    READ_AH(a0, 0, 0, 1); READ_B(b0, 0, 0); READ_B(b1, 0, 1);
    PRIO(1); MFMA_Q(0, 0, a0, b0); PRIO(0);
    BARF();
    // phi2(u): reads a1h1(buf0); MFMA Q01
    READ_AH(a1, 0, 1, 0);
    PRIO(1); MFMA_Q(0, 1, a0, b1); PRIO(0);
    BARF();
    // phi3(u): stage A02(u+2)->buf0; reads a1h2,b0r(buf0); MFMA Q11; guard
    if (s1) { STG_A(0, 0, u + 2); STG_A(0, 2, u + 2); }
    READ_AH(a1, 0, 1, 1); READ_B(b0r, 0, 0);
    PRIO(1); MFMA_Q(1, 1, a1, b1); PRIO(0);
    if (s1) { WAIT_VM(2); } else { WAIT_VM(0); }
    BARF();
    // phi4(u): stage A13(u+2)->buf0; read a0h1(u+1,buf1); MFMA Q10
    if (s1) { STG_A(0, 1, u + 2); STG_A(0, 3, u + 2); }
    READ_AH(a0, 1, 0, 0);
    PRIO(1); MFMA_Q(1, 0, a1, b0r); PRIO(0);
    BARF();
    // phi1(u+1): stage B(u+2)->buf0; reads a0h2,b0,b1(buf1); MFMA Q00
    if (s1) {
      STG_B(0, 0, u + 2); STG_B(0, 1, u + 2);
      STG_B(0, 2, u + 2); STG_B(0, 3, u + 2);
    }
    READ_AH(a0, 1, 0, 1); READ_B(b0, 1, 0); READ_B(b1, 1, 1);
    PRIO(1); MFMA_Q(0, 0, a0, b0); PRIO(0);
    BARF();
    // phi2(u+1): reads a1h1(buf1); MFMA Q01
    READ_AH(a1, 1, 1, 0);
    PRIO(1); MFMA_Q(0, 1, a0, b1); PRIO(0);
    BARF();
    // phi3(u+1): stage A02(u+3)->buf1; reads a1h2,b0r(buf1); MFMA Q11; guard
    if (s2) { STG_A(1, 0, u + 3); STG_A(1, 2, u + 3); }
    READ_AH(a1, 1, 1, 1); READ_B(b0r, 1, 0);
    PRIO(1); MFMA_Q(1, 1, a1, b1); PRIO(0);
    if (s1) {
      if (s2) { WAIT_VM(2); } else { WAIT_VM(0); }
    }
    BARF();
    // phi4(u+1): stage A13(u+3)->buf1; read a0h1(u+2,buf0); MFMA Q10
    if (s2) { STG_A(1, 1, u + 3); STG_A(1, 3, u + 3); }
    if (s1) { READ_AH(a0, 0, 0, 0); }
    PRIO(1); MFMA_Q(1, 0, a1, b0r); PRIO(0);
    BARF();
  }

  // epilogue: row-burst; col=lane&15, row=(lane>>4)*4+r per frag
  const int col0 = n0 + wc * 64 + (lane & 15);
  const int row0 = m0 + wr * 128 + ((lane >> 4) << 2);
  float bj[4];
#pragma unroll
  for (int j = 0; j < 4; ++j) bj[j] = bias[col0 + j * 16];
#pragma unroll
  for (int i = 0; i < 8; ++i) {
#pragma unroll
    for (int r = 0; r < 4; ++r) {
      const size_t ro = (size_t)(row0 + i * 16 + r) * N;
#pragma unroll
      for (int j = 0; j < 4; ++j) {
        C[ro + col0 + j * 16] = acc[i][j][r] + bj[j];
      }
    }
  }
}

// ---------------- fallback (exact f32) ----------------

__global__ __launch_bounds__(256) void k_fallback(
    const float* __restrict__ x, const float* __restrict__ w,
    const float* __restrict__ sc, const float* __restrict__ bias,
    float* __restrict__ out, int T, int O, int K, int nblk, int blk) {
  long long idx = (long long)blockIdx.x * 256 + threadIdx.x;
  if (idx >= (long long)T * O) return;
  int row = (int)(idx / O), col = (int)(idx % O);
  const float* xr = x + (size_t)row * K;
  const float* wr = w + (size_t)col * K;
  const float* sr = sc + (size_t)col * nblk;
  float acc = 0.f;
  for (int b = 0; b < nblk; ++b) {
    float s = bf16tof(bf16rn(sr[b]));
    float part = 0.f;
    for (int k = 0; k < blk; k += 4) {
      float4 xa = *(const float4*)(xr + b * blk + k);
      float4 wa = *(const float4*)(wr + b * blk + k);
      part += xa.x * wa.x + xa.y * wa.y + xa.z * wa.z + xa.w * wa.w;
    }
    acc += part * s;
  }
  out[idx] = acc + bias[col];
}

extern "C" void kernel_launch(void* const* d_in, const int* in_sizes, int n_in,
                              void* d_out, int out_size, void* d_ws, size_t ws_size,
                              hipStream_t stream) {
  const float* x = (const float*)d_in[0];
  const float* w = (const float*)d_in[1];
  const float* sc = (const float*)d_in[2];
  const float* bias = (const float*)d_in[3];
  float* out = (float*)d_out;

  const int x_n = in_sizes[0];
  const int w_n = in_sizes[1];
  const int s_n = in_sizes[2];
  const int O = in_sizes[3];
  const int K = w_n / O;
  const int T = x_n / K;
  const int nblk = s_n / O;
  const int blk = K / nblk;

  const size_t need = (size_t)x_n * 2 + (size_t)w_n * 2;
  const bool tiled_ok = ws_size >= need && (K % (2 * BK)) == 0 &&
                        (T % BM) == 0 && (O % BN) == 0 && (blk % 8) == 0 &&
                        K >= 2 * BK;

  if (tiled_ok) {
    unsigned short* xb = (unsigned short*)d_ws;
    unsigned short* wb = xb + (size_t)x_n;
    int n8x = x_n / 8, n8w = w_n / 8;
    int nprep = n8x + n8w;
    k_prep<<<(nprep + 255) / 256, 256, 0, stream>>>(x, w, sc, xb, wb, K, nblk,
                                                    blk, n8x, n8w);
    hipFuncSetAttribute((const void*)k_gemm256,
                        hipFuncAttributeMaxDynamicSharedMemorySize, 131072);
    dim3 grid((T / BM) * (O / BN));
    k_gemm256<<<grid, 512, 131072, stream>>>(xb, wb, bias, out, T, O, K);
  } else {
    long long total = (long long)T * O;
    dim3 grid((unsigned)((total + 255) / 256));
    k_fallback<<<grid, 256, 0, stream>>>(x, w, sc, bias, out, T, O, K, nblk, blk);
  }
}

// Round 7
// 321.175 us; speedup vs baseline: 1.2415x; 1.2415x over previous
//
#include <hip/hip_runtime.h>
#include <cstdint>
#include <cstddef>

// Round 7: half-kk lookahead pipeline. 8 sub-phases/tile (8 MFMA each),
// palindromic quadrant walk; each sub-phase reads the NEXT sub-phase's
// operand set (16/8 regs) so LDS drain hides under the current MFMA cluster.
// Peak operand liveness 56 VGPR (+128 acc) -> no spill. 2 barriers/tile:
// staging is 1-tile-ahead (all 8 loads at s0/s1, ~6 sub-phases before the
// vm-guard), BAR_B+vm(0) before s7's cross-buffer reads, BAR_A at boundary.
// y = x_bf16 @ (w*bf16(scale))_bf16^T + bias  (x_dq == x exactly: pow2 scales)

typedef __attribute__((ext_vector_type(8))) __bf16 bf16x8;
typedef __attribute__((ext_vector_type(4))) float f32x4;

__device__ __forceinline__ unsigned short bf16rn(float f) {
  unsigned u = __builtin_bit_cast(unsigned, f);
  u = (u + 0x7FFFu + ((u >> 16) & 1u)) >> 16;
  return (unsigned short)u;
}
__device__ __forceinline__ float bf16tof(unsigned short h) {
  unsigned u = ((unsigned)h) << 16;
  return __builtin_bit_cast(float, u);
}
__device__ __forceinline__ void gload_lds16(const void* g, void* l) {
  __builtin_amdgcn_global_load_lds(
      (const __attribute__((address_space(1))) unsigned int*)g,
      (__attribute__((address_space(3))) unsigned int*)l, 16, 0, 0);
}

// ---------------- Phase A: fused prep (x->bf16, w*scale->bf16) -------------

__global__ __launch_bounds__(256) void k_prep(
    const float* __restrict__ x, const float* __restrict__ w,
    const float* __restrict__ sc, unsigned short* __restrict__ xb,
    unsigned short* __restrict__ wb, int K, int nblk, int blk,
    int n8x, int n8w) {
  int t = blockIdx.x * 256 + threadIdx.x;
  if (t < n8x) {
    const float4* p = (const float4*)x + (size_t)t * 2;
    float4 a = p[0], b = p[1];
    uint4 o;
    o.x = (unsigned)bf16rn(a.x) | ((unsigned)bf16rn(a.y) << 16);
    o.y = (unsigned)bf16rn(a.z) | ((unsigned)bf16rn(a.w) << 16);
    o.z = (unsigned)bf16rn(b.x) | ((unsigned)bf16rn(b.y) << 16);
    o.w = (unsigned)bf16rn(b.z) | ((unsigned)bf16rn(b.w) << 16);
    ((uint4*)xb)[t] = o;
  } else if (t - n8x < n8w) {
    int tw = t - n8x;
    size_t base = (size_t)tw * 8;
    int o_row = (int)(base / (size_t)K);
    int k = (int)(base % (size_t)K);
    float s = bf16tof(bf16rn(sc[(size_t)o_row * nblk + k / blk]));
    const float4* p = (const float4*)w + (size_t)tw * 2;
    float4 a = p[0], b = p[1];
    uint4 o;
    o.x = (unsigned)bf16rn(a.x * s) | ((unsigned)bf16rn(a.y * s) << 16);
    o.y = (unsigned)bf16rn(a.z * s) | ((unsigned)bf16rn(a.w * s) << 16);
    o.z = (unsigned)bf16rn(b.x * s) | ((unsigned)bf16rn(b.y * s) << 16);
    o.w = (unsigned)bf16rn(b.z * s) | ((unsigned)bf16rn(b.w * s) << 16);
    ((uint4*)wb)[tw] = o;
  }
}

// ---------------- Phase B: 256^2 half-kk lookahead GEMM --------------------
// C[M][N]=A[M][K]*B[N][K]^T + bias. 512 thr = 8 waves (2Mx4N).
// LDS 128 KiB: 2 bufs x (A[256][64]+B[256][64]) bf16, XOR-swizzled
// (byte ^= (row&7)<<4, inverse-applied on global source, rule 21).

#define BM 256
#define BN 256
#define BK 64

#define BARF()                                  \
  do {                                          \
    __builtin_amdgcn_s_barrier();               \
    asm volatile("" ::: "memory");              \
    __builtin_amdgcn_sched_barrier(0);          \
  } while (0)
#define WAIT_VM(n) asm volatile("s_waitcnt vmcnt(" #n ")" ::: "memory")
#define SCHEDB() __builtin_amdgcn_sched_barrier(0)
#define PRIO(p) __builtin_amdgcn_s_setprio(p)

#define STG_A(buf, q, tile)                                               \
  gload_lds16(Ag + (size_t)(q) * 64 * Ks + (size_t)(tile) * BK,           \
              smem + (buf) * 65536 + (q) * 8192 + tid16)
#define STG_B(buf, q, tile)                                               \
  gload_lds16(Bg + (size_t)(q) * 64 * Ks + (size_t)(tile) * BK,           \
              smem + (buf) * 65536 + 32768 + (q) * 8192 + tid16)

// half-kk A set: 4 frags x 1 kk (4 x ds_read_b128, 16 VGPR)
#define READ_A1(dst, buf, qm, KO)                                         \
  _Pragma("unroll") for (int i_ = 0; i_ < 4; ++i_) {                      \
    dst[i_] = *(const bf16x8*)(smem + (buf) * 65536 +                     \
        (wr * 128 + (qm) * 64 + i_ * 16 + lr) * 128 + (KO));              \
  }
// half-kk B set: 2 frags x 1 kk (2 x ds_read_b128, 8 VGPR)
#define READ_B1(dst, buf, qn, KO)                                         \
  _Pragma("unroll") for (int j_ = 0; j_ < 2; ++j_) {                      \
    dst[j_] = *(const bf16x8*)(smem + (buf) * 65536 + 32768 +             \
        (wc * 64 + (qn) * 32 + j_ * 16 + lr) * 128 + (KO));               \
  }
// 8 MFMA: quadrant (qm,qn), single kk
#define MFMA8(qm, qn, aset, bset)                                         \
  _Pragma("unroll") for (int i_ = 0; i_ < 4; ++i_)                        \
  _Pragma("unroll") for (int j_ = 0; j_ < 2; ++j_)                        \
    acc[(qm) * 4 + i_][(qn) * 2 + j_] =                                   \
        __builtin_amdgcn_mfma_f32_16x16x32_bf16(                          \
            aset[i_], bset[j_],                                           \
            acc[(qm) * 4 + i_][(qn) * 2 + j_], 0, 0, 0);

// one tile: buf p holds tile tt; stage tile tt+1 -> buf q at s0/s1.
// walk: s0 Q00k0 | s1 Q01k0 | s2 Q11k0 | s3 Q10k0 | s4 Q10k1 | s5 Q11k1 |
//       s6 Q01k1 | [vm+BAR_B] s7 Q00k1 (+cross-buffer reads) | BAR_A
#define TILE8(p, q, tt, NEXT_OK)                                          \
  do {                                                                    \
    /* s0 */                                                              \
    if (NEXT_OK) {                                                        \
      STG_A(q, 0, (tt) + 1); STG_A(q, 1, (tt) + 1);                       \
      STG_A(q, 2, (tt) + 1); STG_A(q, 3, (tt) + 1);                       \
    }                                                                     \
    READ_B1(bB, p, 1, ko0);                                               \
    PRIO(1); MFMA8(0, 0, aA, bA); PRIO(0); SCHEDB();                      \
    /* s1 */                                                              \
    if (NEXT_OK) {                                                        \
      STG_B(q, 0, (tt) + 1); STG_B(q, 1, (tt) + 1);                       \
      STG_B(q, 2, (tt) + 1); STG_B(q, 3, (tt) + 1);                       \
    }                                                                     \
    READ_A1(aB, p, 1, ko0);                                               \
    PRIO(1); MFMA8(0, 1, aA, bB); PRIO(0); SCHEDB();                      \
    /* s2 */                                                              \
    READ_B1(bC, p, 0, ko1);                                               \
    PRIO(1); MFMA8(1, 1, aB, bB); PRIO(0); SCHEDB();                      \
    /* s3 */                                                              \
    READ_A1(aA, p, 1, ko1);                                               \
    PRIO(1); MFMA8(1, 0, aB, bA); PRIO(0); SCHEDB();                      \
    /* s4 */                                                              \
    READ_B1(bB, p, 1, ko1);                                               \
    PRIO(1); MFMA8(1, 0, aA, bC); PRIO(0); SCHEDB();                      \
    /* s5 */                                                              \
    READ_A1(aB, p, 0, ko1);                                               \
    PRIO(1); MFMA8(1, 1, aA, bB); PRIO(0); SCHEDB();                      \
    /* s6 */                                                              \
    PRIO(1); MFMA8(0, 1, aB, bB); PRIO(0); SCHEDB();                      \
    if (NEXT_OK) { WAIT_VM(0); }                                          \
    BARF();                                                               \
    /* s7 */                                                              \
    if (NEXT_OK) { READ_A1(aA, q, 0, ko0); READ_B1(bA, q, 0, ko0); }      \
    PRIO(1); MFMA8(0, 0, aB, bC); PRIO(0); SCHEDB();                      \
    BARF();                                                               \
  } while (0)

__global__ __launch_bounds__(512, 2) void k_gemm256(
    const unsigned short* __restrict__ A, const unsigned short* __restrict__ B,
    const float* __restrict__ bias, float* __restrict__ C,
    int M, int N, int K) {
  extern __shared__ __align__(16) char smem[];

  const int nbn = N / BN;
  const int nwg = gridDim.x;
  int bid = blockIdx.x;
  int wg = bid;
  if ((nwg & 7) == 0) wg = (bid & 7) * (nwg >> 3) + (bid >> 3);  // T1
  const int m0 = (wg / nbn) * BM;
  const int n0 = (wg % nbn) * BN;

  const int tid = threadIdx.x;
  const int lane = tid & 63;
  const int wid = tid >> 6;
  const int wr = wid >> 2;
  const int wc = wid & 3;
  const int lr = lane & 15;
  const int ko0 = (((lane >> 4) * 16) ^ ((lane & 7) << 4));
  const int ko1 = ((64 | ((lane >> 4) * 16)) ^ ((lane & 7) << 4));
  const int tid16 = tid * 16;

  const int srow = tid >> 3;
  const int sgran = (tid & 7) ^ (srow & 7);  // inverse swizzle on source
  const size_t Ks = (size_t)K;
  const unsigned short* Ag = A + (size_t)(m0 + srow) * Ks + sgran * 8;
  const unsigned short* Bg = B + (size_t)(n0 + srow) * Ks + sgran * 8;

  f32x4 acc[8][4] = {};
  bf16x8 aA[4], aB[4], bA[2], bB[2], bC[2];

  const int NT = K / BK;      // even (launcher guards K % 128 == 0)
  const int NITER = NT / 2;

  // prologue: stage t0 -> buf0, drain, read s0 operands (aA=a0k0, bA=b0k0)
  STG_A(0, 0, 0); STG_A(0, 1, 0); STG_A(0, 2, 0); STG_A(0, 3, 0);
  STG_B(0, 0, 0); STG_B(0, 1, 0); STG_B(0, 2, 0); STG_B(0, 3, 0);
  WAIT_VM(0);
  BARF();
  READ_A1(aA, 0, 0, ko0);
  READ_B1(bA, 0, 0, ko0);

  for (int it = 0; it < NITER; ++it) {
    const int t0 = 2 * it;
    const bool last = (it + 1) == NITER;
    TILE8(0, 1, t0, true);          // even tile in buf0; stages t0+1
    TILE8(1, 0, t0 + 1, !last);     // odd tile in buf1; stages t0+2
  }

  // epilogue: row-burst; col=lane&15, row=(lane>>4)*4+r per frag
  const int col0 = n0 + wc * 64 + (lane & 15);
  const int row0 = m0 + wr * 128 + ((lane >> 4) << 2);
  float bj[4];
#pragma unroll
  for (int j = 0; j < 4; ++j) bj[j] = bias[col0 + j * 16];
#pragma unroll
  for (int i = 0; i < 8; ++i) {
#pragma unroll
    for (int r = 0; r < 4; ++r) {
      const size_t ro = (size_t)(row0 + i * 16 + r) * N;
#pragma unroll
      for (int j = 0; j < 4; ++j) {
        C[ro + col0 + j * 16] = acc[i][j][r] + bj[j];
      }
    }
  }
}

// ---------------- fallback (exact f32) ----------------

__global__ __launch_bounds__(256) void k_fallback(
    const float* __restrict__ x, const float* __restrict__ w,
    const float* __restrict__ sc, const float* __restrict__ bias,
    float* __restrict__ out, int T, int O, int K, int nblk, int blk) {
  long long idx = (long long)blockIdx.x * 256 + threadIdx.x;
  if (idx >= (long long)T * O) return;
  int row = (int)(idx / O), col = (int)(idx % O);
  const float* xr = x + (size_t)row * K;
  const float* wr = w + (size_t)col * K;
  const float* sr = sc + (size_t)col * nblk;
  float acc = 0.f;
  for (int b = 0; b < nblk; ++b) {
    float s = bf16tof(bf16rn(sr[b]));
    float part = 0.f;
    for (int k = 0; k < blk; k += 4) {
      float4 xa = *(const float4*)(xr + b * blk + k);
      float4 wa = *(const float4*)(wr + b * blk + k);
      part += xa.x * wa.x + xa.y * wa.y + xa.z * wa.z + xa.w * wa.w;
    }
    acc += part * s;
  }
  out[idx] = acc + bias[col];
}

extern "C" void kernel_launch(void* const* d_in, const int* in_sizes, int n_in,
                              void* d_out, int out_size, void* d_ws, size_t ws_size,
                              hipStream_t stream) {
  const float* x = (const float*)d_in[0];
  const float* w = (const float*)d_in[1];
  const float* sc = (const float*)d_in[2];
  const float* bias = (const float*)d_in[3];
  float* out = (float*)d_out;

  const int x_n = in_sizes[0];
  const int w_n = in_sizes[1];
  const int s_n = in_sizes[2];
  const int O = in_sizes[3];
  const int K = w_n / O;
  const int T = x_n / K;
  const int nblk = s_n / O;
  const int blk = K / nblk;

  const size_t need = (size_t)x_n * 2 + (size_t)w_n * 2;
  const bool tiled_ok = ws_size >= need && (K % (2 * BK)) == 0 &&
                        (T % BM) == 0 && (O % BN) == 0 && (blk % 8) == 0 &&
                        K >= 2 * BK;

  if (tiled_ok) {
    unsigned short* xb = (unsigned short*)d_ws;
    unsigned short* wb = xb + (size_t)x_n;
    int n8x = x_n / 8, n8w = w_n / 8;
    int nprep = n8x + n8w;
    k_prep<<<(nprep + 255) / 256, 256, 0, stream>>>(x, w, sc, xb, wb, K, nblk,
                                                    blk, n8x, n8w);
    hipFuncSetAttribute((const void*)k_gemm256,
                        hipFuncAttributeMaxDynamicSharedMemorySize, 131072);
    dim3 grid((T / BM) * (O / BN));
    k_gemm256<<<grid, 512, 131072, stream>>>(xb, wb, bias, out, T, O, K);
  } else {
    long long total = (long long)T * O;
    dim3 grid((unsigned)((total + 255) / 256));
    k_fallback<<<grid, 256, 0, stream>>>(x, w, sc, bias, out, T, O, K, nblk, blk);
  }
}